// Round 8
// baseline (194.869 us; speedup 1.0000x reference)
//
#include <hip/hip_runtime.h>
#include <stdint.h>

#define BATCH 4
#define CINCH 3
#define HIN 128
#define WIN 128
#define NN 4096      // 64*64 output nodes per batch
#define CF 64        // feature channels
#define KNN 7

typedef unsigned short u16;
typedef unsigned u32;
typedef unsigned long long u64;
typedef __attribute__((ext_vector_type(8))) short bf16x8;
typedef __attribute__((ext_vector_type(4))) float f32x4;

// ---------------------------------------------------------------- helpers
__device__ __forceinline__ u64 u64min(u64 a, u64 b) { return a < b ? a : b; }
__device__ __forceinline__ u32 u32min(u32 a, u32 b) { return a < b ? a : b; }

__device__ __forceinline__ u32 med3_u32(u32 a, u32 b, u32 c) {
    u32 d;
    asm("v_med3_u32 %0, %1, %2, %3" : "=v"(d) : "v"(a), "v"(b), "v"(c));
    return d;
}

// branchless sorted top-8 insert (ascending); bitwise-equivalent result to the
// conditional 3-op-per-slot insert (keys are unique within a stream).
__device__ __forceinline__ void insert8_med3(u32* l, u32 k) {
    l[7] = med3_u32(l[6], l[7], k);
    l[6] = med3_u32(l[5], l[6], k);
    l[5] = med3_u32(l[4], l[5], k);
    l[4] = med3_u32(l[3], l[4], k);
    l[3] = med3_u32(l[2], l[3], k);
    l[2] = med3_u32(l[1], l[2], k);
    l[1] = med3_u32(l[0], l[1], k);
    l[0] = u32min(l[0], k);
}

template <int M>
__device__ __forceinline__ void insertM64(u64* lst, u64 k) {
    u64 cur = k;
#pragma unroll
    for (int i = 0; i < M; ++i) {
        u64 lo = u64min(lst[i], cur);
        u64 hi = (lst[i] < cur) ? cur : lst[i];
        lst[i] = lo;
        cur = hi;
    }
}

// ------------------------------------------------ K1: conv + sq + bf16 quant
// One wave = one node (c == lane). acc chain bitwise-identical to prior rounds.
__global__ __launch_bounds__(256) void conv_fused_kernel(
    const float* __restrict__ x, const float* __restrict__ w,
    const float* __restrict__ bias, float* __restrict__ y,
    u16* __restrict__ ybf, float* __restrict__ sq) {
    __shared__ float ws[CF * CINCH * 9];
    __shared__ float bs[CF];
    for (int i = threadIdx.x; i < CF * CINCH * 9; i += 256) ws[i] = w[i];
    if (threadIdx.x < CF) bs[threadIdx.x] = bias[threadIdx.x];
    __syncthreads();

    int gid = blockIdx.x * 256 + threadIdx.x;   // ((b*4096)+n)*64 + c
    int c = gid & 63;                            // == lane
    int n = (gid >> 6) & (NN - 1);
    int b = gid >> 18;
    int oh = n >> 6, ow = n & 63;
    const float* xb = x + (size_t)b * CINCH * HIN * WIN;
    float acc = bs[c];
#pragma unroll
    for (int cin = 0; cin < CINCH; ++cin) {
#pragma unroll
        for (int kh = 0; kh < 3; ++kh) {
            int ih = oh * 2 - 1 + kh;
            if (ih < 0 || ih >= HIN) continue;
#pragma unroll
            for (int kw = 0; kw < 3; ++kw) {
                int iw = ow * 2 - 1 + kw;
                if (iw < 0 || iw >= WIN) continue;
                acc += xb[(cin * HIN + ih) * WIN + iw] *
                       ws[(c * CINCH + cin) * 9 + kh * 3 + kw];
            }
        }
    }
    y[(size_t)gid] = acc;

    // bf16 RNE quant (same formula as prior rounds)
    uint32_t u = __float_as_uint(acc);
    ybf[(size_t)gid] = (u16)((u + 0x7fffu + ((u >> 16) & 1u)) >> 16);

    // sq: wave tree-reduce of acc^2 (c == lane spans the channel dim)
    float s = acc * acc;
#pragma unroll
    for (int off = 32; off; off >>= 1) s += __shfl_xor(s, off, 64);
    if (c == 0) sq[gid >> 6] = s;
}

// ------------------------------------------------ K2: heterogeneous mega-kernel
// 5120 blocks: bid%5==4 -> screen-block sb=bid/5 (1024 of them, write idx to ws);
// else zero-block zb=(bid/5)*4+(bid%5) (4096 of them, 64 KB zero slice of adj).
// Interleaving keeps HBM (zeros) and VALU (screen) busy simultaneously.
__global__ __launch_bounds__(256, 4) void mega_kernel(
    const u16* __restrict__ ybf, const float* __restrict__ yf,
    const float* __restrict__ sq, float4* __restrict__ adj4,
    u32* __restrict__ idxg) {
    __shared__ u32 mlds[16 * 129];       // 8.25 KB padded: [row][src*8+q]
    __shared__ u64 ckey[16][32];         // 4 KB exact rescore keys
    __shared__ u32 cidx[16][32];         // 2 KB candidate cols

    const int bid = blockIdx.x;
    const int m5 = bid % 5;
    const int tid = threadIdx.x;

    if (m5 != 4) {
        // ---- zero-fill block: contiguous 64 KB slice
        const int zb = (bid / 5) * 4 + m5;
        float4* dst = adj4 + (size_t)zb * 4096;
        const float4 z = make_float4(0.f, 0.f, 0.f, 0.f);
#pragma unroll
        for (int k = 0; k < 16; ++k) dst[k * 256 + tid] = z;
        return;
    }

    // ---- screen block
    const int sb = bid / 5;              // 0..1023
    const int b = sb >> 8;
    const int r0 = (sb & 255) << 4;      // 16 rows per block
    const int w = tid >> 6, lane = tid & 63;
    const int lc = lane & 15, g = lane >> 4;
    const size_t nb = (size_t)b * NN;

    // B-operand: this block's 16 rows, K=64 in 2 chunks
    const int row = r0 + lc;
    bf16x8 rf0 = *(const bf16x8*)(ybf + (nb + row) * CF + g * 8);
    bf16x8 rf1 = *(const bf16x8*)(ybf + (nb + row) * CF + 32 + g * 8);
    const float sqr = sq[nb + row];

    u32 lst[8];
#pragma unroll
    for (int q = 0; q < 8; ++q) lst[q] = 0xFFFFFFFFu;

    const f32x4 zro = {0.f, 0.f, 0.f, 0.f};
    const int c0 = w * 1024;
    const size_t cb = (nb + c0 + lc) * CF + (size_t)g * 8;

    bf16x8 na0 = *(const bf16x8*)(ybf + cb);
    bf16x8 na1 = *(const bf16x8*)(ybf + cb + 32);
    for (int ct = 0; ct < 64; ++ct) {
        bf16x8 a0 = na0, a1 = na1;
        if (ct < 63) {
            size_t nxt = cb + (size_t)(ct + 1) * 16 * CF;
            na0 = *(const bf16x8*)(ybf + nxt);
            na1 = *(const bf16x8*)(ybf + nxt + 32);
        }
        const int cbase = c0 + ct * 16;
        float4 sc = *(const float4*)&sq[nb + cbase + g * 4];
        float scv[4] = {sc.x, sc.y, sc.z, sc.w};
        f32x4 acc = __builtin_amdgcn_mfma_f32_16x16x32_bf16(a0, rf0, zro, 0, 0, 0);
        acc = __builtin_amdgcn_mfma_f32_16x16x32_bf16(a1, rf1, acc, 0, 0, 0);
#pragma unroll
        for (int r = 0; r < 4; ++r) {
            float d2a = fmaxf((sqr + scv[r]) - 2.f * acc[r], 0.f);
            u32 key = (__float_as_uint(d2a) & 0xFFFFFF00u) | (u32)(ct * 4 + r);
            insert8_med3(lst, key);   // branchless; same final list
        }
    }

    // dump per-lane lists: row = lc, src = w*4+g
#pragma unroll
    for (int q = 0; q < 8; ++q)
        mlds[lc * 129 + (w * 4 + g) * 8 + q] = lst[q];
    __syncthreads();

    // phase M: 4 threads/row, each merges 4 sources -> top-8 (trunc-key + col order)
    if (tid < 64) {
        const int mrow = tid >> 2, s4 = tid & 3;
        u64 top8[8];
#pragma unroll
        for (int q = 0; q < 8; ++q) top8[q] = ~0ull;
#pragma unroll
        for (int s = 0; s < 4; ++s) {
            const int src = s4 * 4 + s;
            const u32 colhi = (src >> 2) * 1024 + (src & 3) * 4;
#pragma unroll
            for (int q = 0; q < 8; ++q) {
                u32 k = mlds[mrow * 129 + src * 8 + q];
                u32 idx8 = k & 0xFFu;
                u32 col = colhi + (idx8 >> 2) * 16 + (idx8 & 3);
                u64 mk = ((u64)(k & 0xFFFFFF00u) << 24) | col;
                if (mk < top8[7]) insertM64<8>(top8, mk);
            }
        }
#pragma unroll
        for (int q = 0; q < 8; ++q)
            cidx[mrow][s4 * 8 + q] = (u32)(top8[q] & 0xFFFu);
    }
    __syncthreads();

    // phase R: exact f32 rescore (trusted chain), 16 threads/row x 2 cands
    {
        const int rrow = tid >> 4, s = tid & 15;
        const float4* yr = (const float4*)(yf + (nb + r0 + rrow) * CF);
        const float sr = sq[nb + r0 + rrow];
#pragma unroll
        for (int j2 = 0; j2 < 2; ++j2) {
            const int q = s * 2 + j2;
            const u32 col = cidx[rrow][q];
            const float4* yc = (const float4*)(yf + (nb + col) * CF);
            float a = 0.f;
#pragma unroll
            for (int k = 0; k < 16; ++k) {
                float4 av = yr[k], bv = yc[k];
                a += av.x * bv.x;
                a += av.y * bv.y;
                a += av.z * bv.z;
                a += av.w * bv.w;
            }
            float d2 = (sr + sq[nb + col]) - 2.0f * a;
            float dd = sqrtf(fmaxf(d2, 0.0f));
            ckey[rrow][q] = ((u64)__float_as_uint(dd) << 32) | col;
        }
    }
    __syncthreads();

    // phase F: exact top-7 of 32 candidates -> idx to ws
    if (tid < 16) {
        u64 t7[KNN];
#pragma unroll
        for (int q = 0; q < KNN; ++q) t7[q] = ~0ull;
#pragma unroll
        for (int q = 0; q < 32; ++q) {
            u64 k = ckey[tid][q];
            if (k < t7[KNN - 1]) insertM64<KNN>(t7, k);
        }
        u32* dst = idxg + (nb + r0 + tid) * 8;
#pragma unroll
        for (int q = 0; q < KNN; ++q) dst[q] = (u32)(t7[q] & 0xFFFFFFFFu);
    }
}

// ------------------------------------------------ K3: ones (zeros already laid)
__global__ __launch_bounds__(256) void ones_kernel(const u32* __restrict__ idxg,
                                                   float* __restrict__ adj) {
    int grow = blockIdx.x * 256 + threadIdx.x;   // 0..16383
    const u32* ip = idxg + (size_t)grow * 8;
    float* rp = adj + (size_t)grow * NN;
#pragma unroll
    for (int q = 0; q < KNN; ++q) rp[ip[q]] = 1.0f;
}

// ------------------------------------------------ launcher
extern "C" void kernel_launch(void* const* d_in, const int* in_sizes, int n_in,
                              void* d_out, int out_size, void* d_ws, size_t ws_size,
                              hipStream_t stream) {
    const float* x = (const float*)d_in[0];
    const float* w = (const float*)d_in[1];
    const float* bias = (const float*)d_in[2];

    float* y = (float*)d_out;                               // [4][4096][64]
    float* adj = (float*)d_out + (size_t)BATCH * NN * CF;   // [4][4096][4096]

    float* sq = (float*)d_ws;                               // 64 KB
    u16* ybf = (u16*)((char*)d_ws + 65536);                 // 2 MB bf16 features
    u32* idxg = (u32*)((char*)d_ws + 65536 + 2097152);      // 512 KB idx[16384][8]

    conv_fused_kernel<<<4096, 256, 0, stream>>>(x, w, bias, y, ybf, sq);
    mega_kernel<<<5120, 256, 0, stream>>>(ybf, y, sq, (float4*)adj, idxg);
    ones_kernel<<<64, 256, 0, stream>>>(idxg, adj);
}

// Round 9
// 156.347 us; speedup vs baseline: 1.2464x; 1.2464x over previous
//
#include <hip/hip_runtime.h>
#include <stdint.h>

#define BATCH 4
#define CINCH 3
#define HIN 128
#define WIN 128
#define NN 4096      // 64*64 output nodes per batch
#define CF 64        // feature channels
#define KNN 7

typedef unsigned short u16;
typedef unsigned u32;
typedef unsigned long long u64;
typedef __attribute__((ext_vector_type(8))) short bf16x8;
typedef __attribute__((ext_vector_type(4))) float f32x4;

// ---------------------------------------------------------------- helpers
__device__ __forceinline__ u64 u64min(u64 a, u64 b) { return a < b ? a : b; }
__device__ __forceinline__ u32 u32min(u32 a, u32 b) { return a < b ? a : b; }

template <int M>
__device__ __forceinline__ void insertM64(u64* lst, u64 k) {
    u64 cur = k;
#pragma unroll
    for (int i = 0; i < M; ++i) {
        u64 lo = u64min(lst[i], cur);
        u64 hi = (lst[i] < cur) ? cur : lst[i];
        lst[i] = lo;
        cur = hi;
    }
}

template <int M>
__device__ __forceinline__ void insertM32(u32* lst, u32 k) {
    u32 cur = k;
#pragma unroll
    for (int i = 0; i < M; ++i) {
        u32 lo = u32min(lst[i], cur);
        u32 hi = (lst[i] < cur) ? cur : lst[i];
        lst[i] = lo;
        cur = hi;
    }
}

// ------------------------------------------------ K1: conv + sq + bf16 quant
// One wave = one node (c == lane). acc chain bitwise-identical to prior rounds.
__global__ __launch_bounds__(256) void conv_fused_kernel(
    const float* __restrict__ x, const float* __restrict__ w,
    const float* __restrict__ bias, float* __restrict__ y,
    u16* __restrict__ ybf, float* __restrict__ sq) {
    __shared__ float ws[CF * CINCH * 9];
    __shared__ float bs[CF];
    for (int i = threadIdx.x; i < CF * CINCH * 9; i += 256) ws[i] = w[i];
    if (threadIdx.x < CF) bs[threadIdx.x] = bias[threadIdx.x];
    __syncthreads();

    int gid = blockIdx.x * 256 + threadIdx.x;   // ((b*4096)+n)*64 + c
    int c = gid & 63;                            // == lane
    int n = (gid >> 6) & (NN - 1);
    int b = gid >> 18;
    int oh = n >> 6, ow = n & 63;
    const float* xb = x + (size_t)b * CINCH * HIN * WIN;
    float acc = bs[c];
#pragma unroll
    for (int cin = 0; cin < CINCH; ++cin) {
#pragma unroll
        for (int kh = 0; kh < 3; ++kh) {
            int ih = oh * 2 - 1 + kh;
            if (ih < 0 || ih >= HIN) continue;
#pragma unroll
            for (int kw = 0; kw < 3; ++kw) {
                int iw = ow * 2 - 1 + kw;
                if (iw < 0 || iw >= WIN) continue;
                acc += xb[(cin * HIN + ih) * WIN + iw] *
                       ws[(c * CINCH + cin) * 9 + kh * 3 + kw];
            }
        }
    }
    y[(size_t)gid] = acc;

    // bf16 RNE quant (same formula as prior rounds)
    uint32_t u = __float_as_uint(acc);
    ybf[(size_t)gid] = (u16)((u + 0x7fffu + ((u >> 16) & 1u)) >> 16);

    // sq: wave tree-reduce of acc^2 (c == lane spans the channel dim)
    float s = acc * acc;
#pragma unroll
    for (int off = 32; off; off >>= 1) s += __shfl_xor(s, off, 64);
    if (c == 0) sq[gid >> 6] = s;
}

// ------------------------------------------------ K2: screen quarter + zeros
// 4096 blocks = 4 batches x 256 row-tiles x 4 col-quarters. Block: 16 rows x
// 1024 cols (16 iters/wave). Front-loaded zero stores (64 KB/block) drain
// under the compute loop. Emits per-row quarter-top-8 (u64 trunc-key|col) to
// ws. Candidate set per row across 4 quarters is bit-identical to R7's.
__global__ __launch_bounds__(256) void screen_part_kernel(
    const u16* __restrict__ ybf, const float* __restrict__ sq,
    float* __restrict__ adj, u64* __restrict__ qkeys) {
    __shared__ u32 mlds[16 * 129];       // 8.25 KB padded: [row][src*8+q]
    __shared__ u64 m2[16][4][8];         // 4 KB phase-M partials

    const int bid = blockIdx.x;
    const int b = bid >> 10;
    const int rem = bid & 1023;
    const int rt = rem >> 2, qc = rem & 3;
    const int r0 = rt << 4;              // 16 rows per block
    const int tid = threadIdx.x, w = tid >> 6, lane = tid & 63;
    const int lc = lane & 15, g = lane >> 4;
    const size_t nb = (size_t)b * NN;

    // B-operand: this block's 16 rows, K=64 in 2 chunks
    const int row = r0 + lc;
    bf16x8 rf0 = *(const bf16x8*)(ybf + (nb + row) * CF + g * 8);
    bf16x8 rf1 = *(const bf16x8*)(ybf + (nb + row) * CF + 32 + g * 8);
    const float sqr = sq[nb + row];

    const int c0 = qc * 1024 + w * 256;
    const size_t cb = (nb + c0 + lc) * CF + (size_t)g * 8;
    bf16x8 na0 = *(const bf16x8*)(ybf + cb);
    bf16x8 na1 = *(const bf16x8*)(ybf + cb + 32);

    // front-loaded zeros: this block's 16-row x 1024-col quarter of adj
    {
        const float4 z = make_float4(0.f, 0.f, 0.f, 0.f);
#pragma unroll
        for (int jr = 0; jr < 4; ++jr) {
            float4* dst = (float4*)(adj + (nb + r0 + w * 4 + jr) * NN + qc * 1024);
#pragma unroll
            for (int k = 0; k < 4; ++k) dst[lane + k * 64] = z;
        }
    }

    u32 lst[8];
#pragma unroll
    for (int q = 0; q < 8; ++q) lst[q] = 0xFFFFFFFFu;

    const f32x4 zro = {0.f, 0.f, 0.f, 0.f};
    for (int ct = 0; ct < 16; ++ct) {
        bf16x8 a0 = na0, a1 = na1;
        if (ct < 15) {
            size_t nxt = cb + (size_t)(ct + 1) * 16 * CF;
            na0 = *(const bf16x8*)(ybf + nxt);
            na1 = *(const bf16x8*)(ybf + nxt + 32);
        }
        const int cbase = c0 + ct * 16;
        float4 sc = *(const float4*)&sq[nb + cbase + g * 4];
        float scv[4] = {sc.x, sc.y, sc.z, sc.w};
        f32x4 acc = __builtin_amdgcn_mfma_f32_16x16x32_bf16(a0, rf0, zro, 0, 0, 0);
        acc = __builtin_amdgcn_mfma_f32_16x16x32_bf16(a1, rf1, acc, 0, 0, 0);
#pragma unroll
        for (int r = 0; r < 4; ++r) {
            float d2a = fmaxf((sqr + scv[r]) - 2.f * acc[r], 0.f);
            u32 key = (__float_as_uint(d2a) & 0xFFFFFF00u) | (u32)(ct * 4 + r);
            if (key < lst[7]) insertM32<8>(lst, key);
        }
    }

    // dump per-lane lists: row = lc, src = w*4+g
#pragma unroll
    for (int q = 0; q < 8; ++q)
        mlds[lc * 129 + (w * 4 + g) * 8 + q] = lst[q];
    __syncthreads();

    // phase M: tid<64 -> (row, wave-group s4): merge 4 g-streams -> top-8
    if (tid < 64) {
        const int mrow = tid >> 2, s4 = tid & 3;
        u64 top8[8];
#pragma unroll
        for (int q = 0; q < 8; ++q) top8[q] = ~0ull;
#pragma unroll
        for (int s = 0; s < 4; ++s) {
            const int src = s4 * 4 + s;                       // w=s4, g=s
            const u32 colhi = qc * 1024 + s4 * 256 + s * 4;
#pragma unroll
            for (int q = 0; q < 8; ++q) {
                u32 k = mlds[mrow * 129 + src * 8 + q];
                u32 idx6 = k & 0xFFu;
                u32 col = colhi + (idx6 >> 2) * 16 + (idx6 & 3);
                u64 mk = ((u64)(k & 0xFFFFFF00u) << 24) | col;
                if (mk < top8[7]) insertM64<8>(top8, mk);
            }
        }
#pragma unroll
        for (int q = 0; q < 8; ++q) m2[mrow][s4][q] = top8[q];
    }
    __syncthreads();

    // phase M2: tid<16 -> per-row quarter top-8 -> ws
    if (tid < 16) {
        u64 top8[8];
#pragma unroll
        for (int q = 0; q < 8; ++q) top8[q] = ~0ull;
#pragma unroll
        for (int s4 = 0; s4 < 4; ++s4)
#pragma unroll
            for (int q = 0; q < 8; ++q) {
                u64 k = m2[tid][s4][q];
                if (k < top8[7]) insertM64<8>(top8, k);
            }
        u64* dst = qkeys + ((nb + r0 + tid) * 4 + qc) * 8;
#pragma unroll
        for (int q = 0; q < 8; ++q) dst[q] = top8[q];
    }
}

// ------------------------------------------------ K3: merge quarters + exact rescore + ones
// 1024 blocks x 256 threads, 16 rows/block. Phases R/F identical to R7.
__global__ __launch_bounds__(256) void merge_ones_kernel(
    const u64* __restrict__ qkeys, const float* __restrict__ yf,
    const float* __restrict__ sq, float* __restrict__ adj) {
    __shared__ u64 ckey[16][32];

    const int bid = blockIdx.x;
    const int b = bid >> 8;
    const int r0 = (bid & 255) << 4;
    const int tid = threadIdx.x;
    const size_t nb = (size_t)b * NN;

    // phase R: exact f32 rescore (trusted chain), 16 threads/row x 2 cands
    {
        const int rrow = tid >> 4, s = tid & 15;
        const float4* yr = (const float4*)(yf + (nb + r0 + rrow) * CF);
        const float sr = sq[nb + r0 + rrow];
#pragma unroll
        for (int j2 = 0; j2 < 2; ++j2) {
            const int q = s * 2 + j2;
            const u64 mk = qkeys[((nb + r0 + rrow) * 4 + (q >> 3)) * 8 + (q & 7)];
            const u32 col = (u32)(mk & 0xFFFu);
            const float4* yc = (const float4*)(yf + (nb + col) * CF);
            float a = 0.f;
#pragma unroll
            for (int k = 0; k < 16; ++k) {
                float4 av = yr[k], bv = yc[k];
                a += av.x * bv.x;
                a += av.y * bv.y;
                a += av.z * bv.z;
                a += av.w * bv.w;
            }
            float d2 = (sr + sq[nb + col]) - 2.0f * a;
            float dd = sqrtf(fmaxf(d2, 0.0f));
            ckey[rrow][q] = ((u64)__float_as_uint(dd) << 32) | col;
        }
    }
    __syncthreads();

    // phase F: exact top-7 of 32 candidates -> ones (zeros laid by K2)
    if (tid < 16) {
        u64 t7[KNN];
#pragma unroll
        for (int q = 0; q < KNN; ++q) t7[q] = ~0ull;
#pragma unroll
        for (int q = 0; q < 32; ++q) {
            u64 k = ckey[tid][q];
            if (k < t7[KNN - 1]) insertM64<KNN>(t7, k);
        }
        float* rp = adj + (nb + r0 + tid) * NN;
#pragma unroll
        for (int q = 0; q < KNN; ++q) rp[(u32)(t7[q] & 0xFFFFFFFFu)] = 1.0f;
    }
}

// ------------------------------------------------ launcher
extern "C" void kernel_launch(void* const* d_in, const int* in_sizes, int n_in,
                              void* d_out, int out_size, void* d_ws, size_t ws_size,
                              hipStream_t stream) {
    const float* x = (const float*)d_in[0];
    const float* w = (const float*)d_in[1];
    const float* bias = (const float*)d_in[2];

    float* y = (float*)d_out;                               // [4][4096][64]
    float* adj = (float*)d_out + (size_t)BATCH * NN * CF;   // [4][4096][4096]

    float* sq = (float*)d_ws;                               // 64 KB
    u16* ybf = (u16*)((char*)d_ws + 65536);                 // 2 MB bf16 features
    u64* qkeys = (u64*)((char*)d_ws + 65536 + 2097152);     // 4 MB: [16384][4][8]

    conv_fused_kernel<<<4096, 256, 0, stream>>>(x, w, bias, y, ybf, sq);
    screen_part_kernel<<<4096, 256, 0, stream>>>(ybf, sq, adj, qkeys);
    merge_ones_kernel<<<1024, 256, 0, stream>>>(qkeys, y, sq, adj);
}

// Round 10
// 134.687 us; speedup vs baseline: 1.4468x; 1.1608x over previous
//
#include <hip/hip_runtime.h>
#include <stdint.h>

#define BATCH 4
#define CINCH 3
#define HIN 128
#define WIN 128
#define NN 4096      // 64*64 output nodes per batch
#define CF 64        // feature channels
#define KNN 7

typedef unsigned short u16;
typedef unsigned u32;
typedef unsigned long long u64;
typedef __attribute__((ext_vector_type(8))) short bf16x8;
typedef __attribute__((ext_vector_type(4))) float f32x4;

// ---------------------------------------------------------------- helpers
__device__ __forceinline__ u64 u64min(u64 a, u64 b) { return a < b ? a : b; }
__device__ __forceinline__ u32 u32min(u32 a, u32 b) { return a < b ? a : b; }

__device__ __forceinline__ u32 med3_u32(u32 a, u32 b, u32 c) {
    u32 d;
    asm("v_med3_u32 %0, %1, %2, %3" : "=v"(d) : "v"(a), "v"(b), "v"(c));
    return d;
}

// branchless sorted top-8 insert (ascending); bitwise-equal to the
// conditional shift-insert for any key stream.
__device__ __forceinline__ void insert8_med3(u32* l, u32 k) {
    l[7] = med3_u32(l[6], l[7], k);
    l[6] = med3_u32(l[5], l[6], k);
    l[5] = med3_u32(l[4], l[5], k);
    l[4] = med3_u32(l[3], l[4], k);
    l[3] = med3_u32(l[2], l[3], k);
    l[2] = med3_u32(l[1], l[2], k);
    l[1] = med3_u32(l[0], l[1], k);
    l[0] = u32min(l[0], k);
}

template <int M>
__device__ __forceinline__ void insertM64(u64* lst, u64 k) {
    u64 cur = k;
#pragma unroll
    for (int i = 0; i < M; ++i) {
        u64 lo = u64min(lst[i], cur);
        u64 hi = (lst[i] < cur) ? cur : lst[i];
        lst[i] = lo;
        cur = hi;
    }
}

// ------------------------------------------------ K1: conv + sq + bf16 quant
// One wave = one node (c == lane). acc chain bitwise-identical to prior rounds.
__global__ __launch_bounds__(256) void conv_fused_kernel(
    const float* __restrict__ x, const float* __restrict__ w,
    const float* __restrict__ bias, float* __restrict__ y,
    u16* __restrict__ ybf, float* __restrict__ sq) {
    __shared__ float ws[CF * CINCH * 9];
    __shared__ float bs[CF];
    for (int i = threadIdx.x; i < CF * CINCH * 9; i += 256) ws[i] = w[i];
    if (threadIdx.x < CF) bs[threadIdx.x] = bias[threadIdx.x];
    __syncthreads();

    int gid = blockIdx.x * 256 + threadIdx.x;   // ((b*4096)+n)*64 + c
    int c = gid & 63;                            // == lane
    int n = (gid >> 6) & (NN - 1);
    int b = gid >> 18;
    int oh = n >> 6, ow = n & 63;
    const float* xb = x + (size_t)b * CINCH * HIN * WIN;
    float acc = bs[c];
#pragma unroll
    for (int cin = 0; cin < CINCH; ++cin) {
#pragma unroll
        for (int kh = 0; kh < 3; ++kh) {
            int ih = oh * 2 - 1 + kh;
            if (ih < 0 || ih >= HIN) continue;
#pragma unroll
            for (int kw = 0; kw < 3; ++kw) {
                int iw = ow * 2 - 1 + kw;
                if (iw < 0 || iw >= WIN) continue;
                acc += xb[(cin * HIN + ih) * WIN + iw] *
                       ws[(c * CINCH + cin) * 9 + kh * 3 + kw];
            }
        }
    }
    y[(size_t)gid] = acc;

    // bf16 RNE quant (same formula as prior rounds)
    uint32_t u = __float_as_uint(acc);
    ybf[(size_t)gid] = (u16)((u + 0x7fffu + ((u >> 16) & 1u)) >> 16);

    // sq: wave tree-reduce of acc^2 (c == lane spans the channel dim)
    float s = acc * acc;
#pragma unroll
    for (int off = 32; off; off >>= 1) s += __shfl_xor(s, off, 64);
    if (c == 0) sq[gid >> 6] = s;
}

// ------------------------------------------------ K2: screen + zeros + rescore + ones
// 1024 blocks (4 batches x 256 row-tiles of 16 rows), 256 threads, 4 blocks/CU.
// Hot loop: med3 branchless top-8; 1 zero-store float4/thread/iter placed AFTER
// the prefetch loads (stores pipeline behind loads, drain under compute).
// Selection pipeline bitwise-identical to the R7-passing kernel.
__global__ __launch_bounds__(256, 4) void screen_kernel(
    const u16* __restrict__ ybf, const float* __restrict__ yf,
    const float* __restrict__ sq, float* __restrict__ adj) {
    __shared__ u32 mlds[16 * 129];       // 8.25 KB padded: [row][src*8+q]
    __shared__ u64 ckey[16][32];         // 4 KB exact rescore keys
    __shared__ u32 cidx[16][32];         // 2 KB candidate cols / final idx

    const int bid = blockIdx.x;
    const int b = bid >> 8;
    const int r0 = (bid & 255) << 4;     // 16 rows per block
    const int tid = threadIdx.x, w = tid >> 6, lane = tid & 63;
    const int lc = lane & 15, g = lane >> 4;
    const size_t nb = (size_t)b * NN;

    // B-operand: this block's 16 rows, K=64 in 2 chunks
    const int row = r0 + lc;
    bf16x8 rf0 = *(const bf16x8*)(ybf + (nb + row) * CF + g * 8);
    bf16x8 rf1 = *(const bf16x8*)(ybf + (nb + row) * CF + 32 + g * 8);
    const float sqr = sq[nb + row];

    u32 lst[8];
#pragma unroll
    for (int q = 0; q < 8; ++q) lst[q] = 0xFFFFFFFFu;

    const f32x4 zro = {0.f, 0.f, 0.f, 0.f};
    const int c0 = w * 1024;
    const size_t cb = (nb + c0 + lc) * CF + (size_t)g * 8;

    // zero-store stream: thread covers row r0+(tid>>4), one float4 per iter
    float4* zrow = (float4*)(adj + (nb + r0 + (tid >> 4)) * NN) + (tid & 15);
    const float4 zf4 = make_float4(0.f, 0.f, 0.f, 0.f);

    bf16x8 na0 = *(const bf16x8*)(ybf + cb);
    bf16x8 na1 = *(const bf16x8*)(ybf + cb + 32);
    float4 nsc = *(const float4*)&sq[nb + c0 + g * 4];

    for (int ct = 0; ct < 64; ++ct) {
        bf16x8 a0 = na0, a1 = na1;
        float4 sc = nsc;
        if (ct < 63) {
            size_t nxt = cb + (size_t)(ct + 1) * 16 * CF;
            na0 = *(const bf16x8*)(ybf + nxt);
            na1 = *(const bf16x8*)(ybf + nxt + 32);
            nsc = *(const float4*)&sq[nb + c0 + (ct + 1) * 16 + g * 4];
        }
        zrow[ct * 16] = zf4;   // after prefetch loads: no consume-wait on store

        float scv[4] = {sc.x, sc.y, sc.z, sc.w};
        f32x4 acc = __builtin_amdgcn_mfma_f32_16x16x32_bf16(a0, rf0, zro, 0, 0, 0);
        acc = __builtin_amdgcn_mfma_f32_16x16x32_bf16(a1, rf1, acc, 0, 0, 0);
#pragma unroll
        for (int r = 0; r < 4; ++r) {
            float d2a = fmaxf((sqr + scv[r]) - 2.f * acc[r], 0.f);
            u32 key = (__float_as_uint(d2a) & 0xFFFFFF00u) | (u32)(ct * 4 + r);
            insert8_med3(lst, key);   // branchless, bitwise-same final list
        }
    }

    // dump per-lane lists: row = lc, src = w*4+g
#pragma unroll
    for (int q = 0; q < 8; ++q)
        mlds[lc * 129 + (w * 4 + g) * 8 + q] = lst[q];
    __syncthreads();

    // phase M: 4 threads/row, each merges 4 sources -> top-8 (trunc-key + col order)
    if (tid < 64) {
        const int mrow = tid >> 2, s4 = tid & 3;
        u64 top8[8];
#pragma unroll
        for (int q = 0; q < 8; ++q) top8[q] = ~0ull;
#pragma unroll
        for (int s = 0; s < 4; ++s) {
            const int src = s4 * 4 + s;
            const u32 colhi = (src >> 2) * 1024 + (src & 3) * 4;
#pragma unroll
            for (int q = 0; q < 8; ++q) {
                u32 k = mlds[mrow * 129 + src * 8 + q];
                u32 idx8 = k & 0xFFu;
                u32 col = colhi + (idx8 >> 2) * 16 + (idx8 & 3);
                u64 mk = ((u64)(k & 0xFFFFFF00u) << 24) | col;
                if (mk < top8[7]) insertM64<8>(top8, mk);
            }
        }
#pragma unroll
        for (int q = 0; q < 8; ++q)
            cidx[mrow][s4 * 8 + q] = (u32)(top8[q] & 0xFFFu);
    }
    __syncthreads();

    // phase R: exact f32 rescore (trusted chain), 16 threads/row x 2 cands
    {
        const int rrow = tid >> 4, s = tid & 15;
        const float4* yr = (const float4*)(yf + (nb + r0 + rrow) * CF);
        const float sr = sq[nb + r0 + rrow];
#pragma unroll
        for (int j2 = 0; j2 < 2; ++j2) {
            const int q = s * 2 + j2;
            const u32 col = cidx[rrow][q];
            const float4* yc = (const float4*)(yf + (nb + col) * CF);
            float a = 0.f;
#pragma unroll
            for (int k = 0; k < 16; ++k) {
                float4 av = yr[k], bv = yc[k];
                a += av.x * bv.x;
                a += av.y * bv.y;
                a += av.z * bv.z;
                a += av.w * bv.w;
            }
            float d2 = (sr + sq[nb + col]) - 2.0f * a;
            float dd = sqrtf(fmaxf(d2, 0.0f));
            ckey[rrow][q] = ((u64)__float_as_uint(dd) << 32) | col;
        }
    }
    __syncthreads();

    // phase F: exact top-7 of 32 candidates -> cidx[row][0..6]
    if (tid < 16) {
        u64 t7[KNN];
#pragma unroll
        for (int q = 0; q < KNN; ++q) t7[q] = ~0ull;
#pragma unroll
        for (int q = 0; q < 32; ++q) {
            u64 k = ckey[tid][q];
            if (k < t7[KNN - 1]) insertM64<KNN>(t7, k);
        }
#pragma unroll
        for (int q = 0; q < KNN; ++q)
            cidx[tid][q] = (u32)(t7[q] & 0xFFFFFFFFu);
    }
    __syncthreads();

    // phase O: 7 ones per row (zeros written by this block, drained at barrier)
    if (tid < 16 * KNN) {
        const int orow = tid / KNN, q = tid % KNN;
        u32 col = cidx[orow][q];
        adj[(nb + r0 + orow) * NN + col] = 1.0f;
    }
}

// ------------------------------------------------ launcher
extern "C" void kernel_launch(void* const* d_in, const int* in_sizes, int n_in,
                              void* d_out, int out_size, void* d_ws, size_t ws_size,
                              hipStream_t stream) {
    const float* x = (const float*)d_in[0];
    const float* w = (const float*)d_in[1];
    const float* bias = (const float*)d_in[2];

    float* y = (float*)d_out;                               // [4][4096][64]
    float* adj = (float*)d_out + (size_t)BATCH * NN * CF;   // [4][4096][4096]

    float* sq = (float*)d_ws;                               // 64 KB
    u16* ybf = (u16*)((char*)d_ws + 65536);                 // 2 MB bf16 features

    conv_fused_kernel<<<4096, 256, 0, stream>>>(x, w, bias, y, ybf, sq);
    screen_kernel<<<1024, 256, 0, stream>>>(ybf, y, sq, adj);
}